// Round 14
// baseline (265.056 us; speedup 1.0000x reference)
//
#include <hip/hip_runtime.h>
#include <hip/hip_bf16.h>

// ---------------------------------------------------------------------------
// CrossAttentionBlock — R14: two dispatches.
//  K1 proj_gemm (byte-identical R13): MFMA projections -> Kd, Vtd, Qs.
//  K2 attn_fused: flash attention with (a) INLINE Q-upsample from Qs (kills
//     upsample kernel + Qd buffer), (b) fan-in epilogue: per-row-group
//     counter, single ACQ_REL atomicAdd per block (NO polling — R12's spin
//     barrier was the disaster); the last finisher of each row-group's
//     SPLIT chunks does conv/BN/ReLU for those 128 pixels (overlaps tail).
// R13 residual analysis: 98us spread over upsample+epi+gaps, all
// latency-bound at ~1 block/CU; no kernel above attn's 48us.
// ---------------------------------------------------------------------------

constexpr int B   = 2;
constexpr int N   = 9216;   // 96*96
constexpr int E   = 64;
constexpr int CO  = 32;
constexpr int CT  = 64;
constexpr int KVBLK = 64;

constexpr int KV_BLKS = (B * N) / 128;    // 144 K/V GEMM blocks
constexpr int QS_BLKS = (B * 1024) / 128; // 16 Qs GEMM blocks

typedef _Float16 f16x8 __attribute__((ext_vector_type(8)));
typedef _Float16 f16x4 __attribute__((ext_vector_type(4)));
typedef float    f32x4 __attribute__((ext_vector_type(4)));
typedef unsigned int u32;

#define MFMA(a, b, c) __builtin_amdgcn_mfma_f32_16x16x32_f16((a), (b), (c), 0, 0, 0)

#define GLOAD16(gsrc, ldst)                                                     \
  __builtin_amdgcn_global_load_lds(                                             \
      (const __attribute__((address_space(1))) u32*)(gsrc),                     \
      (__attribute__((address_space(3))) u32*)(ldst), 16, 0, 0)

#define PKRTZ(a, b) __builtin_bit_cast(unsigned, __builtin_amdgcn_cvt_pkrtz((a), (b)))

// exp(s/8) == exp2(s * SC); SC folded into the small Q projection.
#define SC 0.18033688011112042f

// ---------------------------------------------------------------------------
// Kernel 1: MFMA-GEMM projections (byte-identical to R13).
// ---------------------------------------------------------------------------
__global__ __launch_bounds__(256) void proj_gemm_kernel(
    const float* __restrict__ xo,   // [B][32][N]
    const float* __restrict__ kw, const float* __restrict__ kb,
    const float* __restrict__ vw, const float* __restrict__ vb,
    _Float16* __restrict__ K, _Float16* __restrict__ Vt,
    const float* __restrict__ xt,   // [B][64][32][32]
    const float* __restrict__ qw, const float* __restrict__ qb,
    float* __restrict__ Qs)         // [B*1024][64], (acc+qb)*SC
{
  __shared__ u32 Xl[128 * 32];   // 16 KB

  const int tid  = threadIdx.x;
  const int wave = tid >> 6, lane = tid & 63;
  const int r16  = lane & 15, g = lane >> 4;
  const int bid  = blockIdx.x;

  if (bid < KV_BLKS) {
    const int p0 = bid * 128;
    const int b  = p0 / N, n0 = p0 % N;

    {
      const int p  = tid & 127;
      const int ch = tid >> 7;
#pragma unroll
      for (int cc = 0; cc < 8; ++cc) {
        const int c = cc * 4 + ch * 2;
        const float x0 = xo[((size_t)b * CO + c) * N + n0 + p];
        const float x1 = xo[((size_t)b * CO + c + 1) * N + n0 + p];
        Xl[p * 16 + ((c >> 1) ^ (p & 15))] = PKRTZ(x0, x1);
      }
    }
    __syncthreads();

    f16x8 xb[2];
#pragma unroll
    for (int pt = 0; pt < 2; ++pt) {
      const int p = (wave * 2 + pt) * 16 + r16;
      union { u32 u[4]; f16x8 v; } fr;
#pragma unroll
      for (int j = 0; j < 4; ++j)
        fr.u[j] = Xl[p * 16 + ((g * 4 + j) ^ r16)];
      xb[pt] = fr.v;
    }

#pragma unroll
    for (int et = 0; et < 4; ++et) {
      const float* kwe = kw + (size_t)(et * 16 + r16) * 32 + g * 8;
      const f32x4 w0 = *(const f32x4*)(kwe);
      const f32x4 w1 = *(const f32x4*)(kwe + 4);
      union { u32 u[4]; f16x8 v; } af;
      af.u[0] = PKRTZ(w0[0], w0[1]); af.u[1] = PKRTZ(w0[2], w0[3]);
      af.u[2] = PKRTZ(w1[0], w1[1]); af.u[3] = PKRTZ(w1[2], w1[3]);

      const int e0 = et * 16 + 4 * g;
      const float b0 = kb[e0], b1 = kb[e0 + 1], b2 = kb[e0 + 2], b3 = kb[e0 + 3];
#pragma unroll
      for (int pt = 0; pt < 2; ++pt) {
        f32x4 d = (f32x4){0.f, 0.f, 0.f, 0.f};
        d = MFMA(af.v, xb[pt], d);
        const int p = p0 + (wave * 2 + pt) * 16 + r16;
        uint2 pk;
        pk.x = PKRTZ(d[0] + b0, d[1] + b1);
        pk.y = PKRTZ(d[2] + b2, d[3] + b3);
        *(uint2*)(K + (size_t)p * E + e0) = pk;
      }
    }

#pragma unroll
    for (int ot = 0; ot < 2; ++ot) {
      const float* vwo = vw + (size_t)(ot * 16 + r16) * 32 + g * 8;
      const f32x4 w0 = *(const f32x4*)(vwo);
      const f32x4 w1 = *(const f32x4*)(vwo + 4);
      union { u32 u[4]; f16x8 v; } af;
      af.u[0] = PKRTZ(w0[0], w0[1]); af.u[1] = PKRTZ(w0[2], w0[3]);
      af.u[2] = PKRTZ(w1[0], w1[1]); af.u[3] = PKRTZ(w1[2], w1[3]);

      const int o0 = ot * 16 + 4 * g;
      const float b0 = vb[o0], b1 = vb[o0 + 1], b2 = vb[o0 + 2], b3 = vb[o0 + 3];
#pragma unroll
      for (int pt = 0; pt < 2; ++pt) {
        f32x4 d = (f32x4){0.f, 0.f, 0.f, 0.f};
        d = MFMA(af.v, xb[pt], d);
        const int n = n0 + (wave * 2 + pt) * 16 + r16;
        Vt[((size_t)b * CO + o0)     * N + n] = (_Float16)(d[0] + b0);
        Vt[((size_t)b * CO + o0 + 1) * N + n] = (_Float16)(d[1] + b1);
        Vt[((size_t)b * CO + o0 + 2) * N + n] = (_Float16)(d[2] + b2);
        Vt[((size_t)b * CO + o0 + 3) * N + n] = (_Float16)(d[3] + b3);
      }
    }
  } else {
    const int qbid = bid - KV_BLKS;
    const int qp0  = qbid * 128;
    const int b    = qp0 >> 10, p10 = qp0 & 1023;

    {
      const int p  = tid & 127;
      const int ch = tid >> 7;
#pragma unroll
      for (int cc = 0; cc < 16; ++cc) {
        const int c = cc * 4 + ch * 2;
        const float x0 = xt[(((size_t)b * 64 + c) << 10) + p10 + p];
        const float x1 = xt[(((size_t)b * 64 + c + 1) << 10) + p10 + p];
        Xl[p * 32 + ((c >> 1) ^ (p & 31))] = PKRTZ(x0, x1);
      }
    }
    __syncthreads();

    f16x8 xb[2][2];
#pragma unroll
    for (int pt = 0; pt < 2; ++pt) {
      const int pl = (wave * 2 + pt) * 16 + r16;
#pragma unroll
      for (int ks = 0; ks < 2; ++ks) {
        union { u32 u[4]; f16x8 v; } fr;
#pragma unroll
        for (int j = 0; j < 4; ++j)
          fr.u[j] = Xl[pl * 32 + ((ks * 16 + g * 4 + j) ^ (pl & 31))];
        xb[pt][ks] = fr.v;
      }
    }

#pragma unroll
    for (int et = 0; et < 4; ++et) {
      union { u32 u[4]; f16x8 v; } af[2];
#pragma unroll
      for (int ks = 0; ks < 2; ++ks) {
        const float* qwe = qw + (size_t)(et * 16 + r16) * 64 + ks * 32 + g * 8;
        const f32x4 w0 = *(const f32x4*)(qwe);
        const f32x4 w1 = *(const f32x4*)(qwe + 4);
        af[ks].u[0] = PKRTZ(w0[0], w0[1]); af[ks].u[1] = PKRTZ(w0[2], w0[3]);
        af[ks].u[2] = PKRTZ(w1[0], w1[1]); af[ks].u[3] = PKRTZ(w1[2], w1[3]);
      }

      const int e0 = et * 16 + 4 * g;
      const f32x4 qb4 = {qb[e0], qb[e0 + 1], qb[e0 + 2], qb[e0 + 3]};
#pragma unroll
      for (int pt = 0; pt < 2; ++pt) {
        f32x4 d = (f32x4){0.f, 0.f, 0.f, 0.f};
        d = MFMA(af[0].v, xb[pt][0], d);
        d = MFMA(af[1].v, xb[pt][1], d);
        const int pix = qp0 + (wave * 2 + pt) * 16 + r16;
        *(f32x4*)(Qs + (size_t)pix * 64 + e0) = (d + qb4) * SC;
      }
    }
  }
}

// ---------------------------------------------------------------------------
// Kernel 2: fused attention + inline Q-upsample + fan-in epilogue.
// ---------------------------------------------------------------------------
template<int SPLIT>
__global__ __launch_bounds__(256) void attn_fused_kernel(
    const float* __restrict__ Qs,   // [B*1024][64], SC-scaled
    const _Float16* __restrict__ K,
    const _Float16* __restrict__ Vt,
    const float* __restrict__ ow, const float* __restrict__ gm,
    const float* __restrict__ bt, const float* __restrict__ mn,
    const float* __restrict__ vr, float* __restrict__ out,
    _Float16* __restrict__ OutWS,   // [SPLIT][B][N][CO] fp16
    float* __restrict__ SumWS,      // [SPLIT][B][N] f32
    unsigned* __restrict__ ctr)     // [144] fan-in counters (zeroed)
{
  constexpr int MCHUNK = N / SPLIT;
  constexpr int ROUNDS = MCHUNK / KVBLK;

  __shared__ _Float16 Kl[2][KVBLK][64];   // 16 KB
  __shared__ _Float16 Vl[2][CO][KVBLK];   //  8 KB
  __shared__ int lastflag;

  const int tid  = threadIdx.x;
  const int wave = tid >> 6, lane = tid & 63;
  const int r16  = lane & 15, g = lane >> 4;

  const int work  = blockIdx.x;
  const int chunk = work & (SPLIT - 1);
  const int t128  = work / SPLIT;         // 0..143 (row-group x batch)
  const int b     = t128 / 72;
  const int rowbase = (t128 % 72) * 128 + wave * 32;

  const _Float16* Kb = K  + (size_t)b * N * E;
  const _Float16* Vb = Vt + (size_t)b * CO * N;

  const int sub = lane >> 3, c8 = lane & 7;
  const int swz = 8 * (c8 ^ sub);

  const int mstart = chunk * MCHUNK;

  // ---- inline Q upsample: qf from Qs (4-corner interp, L2-hot) ----
  f16x8 qf[2][2];
  {
    const float* Qbase = Qs + ((size_t)b << 16);   // b*1024*64
#pragma unroll
    for (int rt = 0; rt < 2; ++rt) {
      const int n  = rowbase + rt * 16 + r16;
      const int ho = n / 96, wo = n % 96;
      const float sh = (ho + 0.5f) * (1.0f / 3.0f) - 0.5f;
      const float sw = (wo + 0.5f) * (1.0f / 3.0f) - 0.5f;
      int h0 = (int)floorf(sh); const float fh = sh - (float)h0;
      int w0 = (int)floorf(sw); const float fw = sw - (float)w0;
      int h1 = min(h0 + 1, 31); h0 = max(h0, 0);
      int w1 = min(w0 + 1, 31); w0 = max(w0, 0);
      const float c00 = (1.f - fh) * (1.f - fw), c01 = (1.f - fh) * fw;
      const float c10 = fh * (1.f - fw),         c11 = fh * fw;
      const float* p00 = Qbase + (h0 * 32 + w0) * 64;
      const float* p01 = Qbase + (h0 * 32 + w1) * 64;
      const float* p10 = Qbase + (h1 * 32 + w0) * 64;
      const float* p11 = Qbase + (h1 * 32 + w1) * 64;
#pragma unroll
      for (int ks = 0; ks < 2; ++ks) {
        union { u32 u[4]; f16x8 v; } qa;
#pragma unroll
        for (int j4 = 0; j4 < 2; ++j4) {
          const int e0 = ks * 32 + g * 8 + j4 * 4;
          const f32x4 a = *(const f32x4*)(p00 + e0) * c00
                        + *(const f32x4*)(p01 + e0) * c01
                        + *(const f32x4*)(p10 + e0) * c10
                        + *(const f32x4*)(p11 + e0) * c11;
          qa.u[j4 * 2]     = PKRTZ(a[0], a[1]);
          qa.u[j4 * 2 + 1] = PKRTZ(a[2], a[3]);
        }
        qf[rt][ks] = qa.v;
      }
    }
  }

  f16x8 onesf;
#pragma unroll
  for (int i = 0; i < 8; ++i) onesf[i] = (_Float16)1.0f;

  // prologue: stage round 0 into buf 0
  {
    const _Float16* gk = Kb + (size_t)(mstart + 16 * wave + sub) * E + swz;
    GLOAD16(gk,         &Kl[0][16 * wave][0]);
    GLOAD16(gk + 8 * E, &Kl[0][16 * wave + 8][0]);
    const _Float16* gv = Vb + (size_t)(8 * wave + sub) * N + mstart + swz;
    GLOAD16(gv,         &Vl[0][8 * wave][0]);
  }

  f32x4 oacc[2][2];
#pragma unroll
  for (int a = 0; a < 2; ++a)
#pragma unroll
    for (int c = 0; c < 2; ++c) oacc[a][c] = (f32x4){0.f, 0.f, 0.f, 0.f};
  f32x4 sacc[2];
  sacc[0] = (f32x4){0.f, 0.f, 0.f, 0.f};
  sacc[1] = (f32x4){0.f, 0.f, 0.f, 0.f};

  const int rsw   = (r16 & 7) << 4;
  const int kcol0 = ((0 * 64 + g * 16) ^ rsw) >> 1;
  const int kcol1 = ((1 * 64 + g * 16) ^ rsw) >> 1;

  __syncthreads();

  int cur = 0;
  for (int r = 0; r < ROUNDS; ++r) {
    if (r + 1 < ROUNDS) {
      const int m0 = mstart + (r + 1) * KVBLK;
      const _Float16* gk = Kb + (size_t)(m0 + 16 * wave + sub) * E + swz;
      GLOAD16(gk,         &Kl[cur ^ 1][16 * wave][0]);
      GLOAD16(gk + 8 * E, &Kl[cur ^ 1][16 * wave + 8][0]);
      const _Float16* gv = Vb + (size_t)(8 * wave + sub) * N + m0 + swz;
      GLOAD16(gv,         &Vl[cur ^ 1][8 * wave][0]);
    }

#pragma unroll
    for (int it = 0; it < 2; ++it) {
      f16x8 kf[2][2];
#pragma unroll
      for (int mt = 0; mt < 2; ++mt) {
        const int krow = it * 32 + mt * 16 + r16;
        kf[mt][0] = *(const f16x8*)&Kl[cur][krow][kcol0];
        kf[mt][1] = *(const f16x8*)&Kl[cur][krow][kcol1];
      }
      union { f16x4 h[2]; f16x8 v; } vf[2];
#pragma unroll
      for (int ot = 0; ot < 2; ++ot) {
        const int vrow = ot * 16 + r16;
        const int v0 = ((it * 64 + 8 * g) ^ rsw) >> 1;
        const int v1 = ((it * 64 + 32 + 8 * g) ^ rsw) >> 1;
        vf[ot].h[0] = *(const f16x4*)&Vl[cur][vrow][v0];
        vf[ot].h[1] = *(const f16x4*)&Vl[cur][vrow][v1];
      }

#pragma unroll
      for (int rt = 0; rt < 2; ++rt) {
        f32x4 s0 = (f32x4){0.f, 0.f, 0.f, 0.f};
        f32x4 s1 = (f32x4){0.f, 0.f, 0.f, 0.f};
        s0 = MFMA(kf[0][0], qf[rt][0], s0);
        s0 = MFMA(kf[0][1], qf[rt][1], s0);
        s1 = MFMA(kf[1][0], qf[rt][0], s1);
        s1 = MFMA(kf[1][1], qf[rt][1], s1);

        float p0[4], p1[4];
#pragma unroll
        for (int i = 0; i < 4; ++i) {
          p0[i] = __builtin_amdgcn_exp2f(s0[i]);
          p1[i] = __builtin_amdgcn_exp2f(s1[i]);
        }

        union { unsigned u[4]; f16x8 v; } pb;
        pb.u[0] = PKRTZ(p0[0], p0[1]);
        pb.u[1] = PKRTZ(p0[2], p0[3]);
        pb.u[2] = PKRTZ(p1[0], p1[1]);
        pb.u[3] = PKRTZ(p1[2], p1[3]);

        oacc[rt][0] = MFMA(vf[0].v, pb.v, oacc[rt][0]);
        oacc[rt][1] = MFMA(vf[1].v, pb.v, oacc[rt][1]);
        sacc[rt]    = MFMA(onesf,   pb.v, sacc[rt]);
      }
    }

    __syncthreads();
    cur ^= 1;
  }

  // ---- partial stores ----
  _Float16* OW = OutWS + (size_t)(chunk * B + b) * N * CO;
  float*    SW = SumWS + (size_t)(chunk * B + b) * N;
#pragma unroll
  for (int rt = 0; rt < 2; ++rt) {
    const int n = rowbase + rt * 16 + r16;
    if (g == 0) SW[n] = sacc[rt][0];
#pragma unroll
    for (int ot = 0; ot < 2; ++ot) {
      uint2 pko;
      pko.x = PKRTZ(oacc[rt][ot][0], oacc[rt][ot][1]);
      pko.y = PKRTZ(oacc[rt][ot][2], oacc[rt][ot][3]);
      *(uint2*)(OW + (size_t)n * CO + ot * 16 + 4 * g) = pko;
    }
  }

  // ---- fan-in: single device-scope atomic per block (NO polling) ----
  __syncthreads();   // all stores in block issued & drained (vmcnt before barrier)
  if (tid == 0) {
    const unsigned old = __hip_atomic_fetch_add(&ctr[t128], 1u,
                              __ATOMIC_ACQ_REL, __HIP_MEMORY_SCOPE_AGENT);
    lastflag = (old == (unsigned)(SPLIT - 1));
  }
  __syncthreads();

  // ---- last finisher: epilogue for this row-group's 128 pixels ----
  if (lastflag) {
    const int nloc = tid & 127;        // pixel within row-group
    const int th   = tid >> 7;         // t-half (wave-uniform)
    const int n    = (t128 % 72) * 128 + nloc;

    float accf[CO];
#pragma unroll
    for (int o = 0; o < CO; ++o) accf[o] = 0.f;
    float ssum = 0.f;
#pragma unroll 4
    for (int sc = 0; sc < SPLIT; ++sc) {
      const f16x8* src = (const f16x8*)(OutWS + ((size_t)(sc * B + b) * N + n) * CO);
#pragma unroll
      for (int j = 0; j < 4; ++j) {
        const f16x8 c = src[j];
#pragma unroll
        for (int i = 0; i < 8; ++i) accf[j * 8 + i] += (float)c[i];
      }
      ssum += SumWS[(size_t)(sc * B + b) * N + n];
    }
    const float inv = 1.f / ssum;

#pragma unroll 1
    for (int i = 0; i < 32; ++i) {
      const int t = th * 32 + i;   // wave-uniform -> scalar weight loads
      float acc2 = 0.f;
#pragma unroll
      for (int o = 0; o < CO; ++o) acc2 += accf[o] * ow[t * CO + o];
      const float scl = gm[t] * rsqrtf(vr[t] + 1e-5f);
      const float bia = bt[t] - mn[t] * scl;
      const float gv  = acc2 * inv * scl + bia;
      out[(size_t)(b * CT + t) * N + n] = fmaxf(gv, 0.f);
    }
  }
}

// ---------------------------------------------------------------------------
extern "C" void kernel_launch(void* const* d_in, const int* in_sizes, int n_in,
                              void* d_out, int out_size, void* d_ws, size_t ws_size,
                              hipStream_t stream) {
  const float* xt = (const float*)d_in[0];
  const float* xo = (const float*)d_in[1];
  const float* qw = (const float*)d_in[2];
  const float* qb = (const float*)d_in[3];
  const float* kw = (const float*)d_in[4];
  const float* kb = (const float*)d_in[5];
  const float* vw = (const float*)d_in[6];
  const float* vb = (const float*)d_in[7];
  const float* ow = (const float*)d_in[8];
  const float* gm = (const float*)d_in[9];
  const float* bt = (const float*)d_in[10];
  const float* mn = (const float*)d_in[11];
  const float* vr = (const float*)d_in[12];

  char* ws = (char*)d_ws;
  unsigned* ctr = (unsigned*)ws;  ws += 1024;
  _Float16* Kd  = (_Float16*)ws;  ws += (size_t)B * N * E * 2;    // 2.36 MB
  _Float16* Vtd = (_Float16*)ws;  ws += (size_t)B * CO * N * 2;   // 1.18 MB
  float* Qs     = (float*)ws;     ws += (size_t)B * 1024 * 64 * 4;// 0.52 MB
  _Float16* OutWS = (_Float16*)ws;  // SPLIT*B*N*CO*2 (+SumWS f32)
  const size_t base   = (size_t)(ws - (char*)d_ws);
  const size_t need16 = base + (size_t)16 * B * N * (CO * 2 + 4); // ~24.6 MB

  hipMemsetAsync(ctr, 0, 1024, stream);
  proj_gemm_kernel<<<KV_BLKS + QS_BLKS, 256, 0, stream>>>(
      xo, kw, kb, vw, vb, Kd, Vtd, xt, qw, qb, Qs);

  if (ws_size >= need16) {
    float* SumWS = (float*)(OutWS + (size_t)16 * B * N * CO);
    attn_fused_kernel<16><<<(N / 128) * B * 16, 256, 0, stream>>>(
        Qs, Kd, Vtd, ow, gm, bt, mn, vr, (float*)d_out, OutWS, SumWS, ctr);
  } else {
    float* SumWS = (float*)(OutWS + (size_t)8 * B * N * CO);
    attn_fused_kernel<8><<<(N / 128) * B * 8, 256, 0, stream>>>(
        Qs, Kd, Vtd, ow, gm, bt, mn, vr, (float*)d_out, OutWS, SumWS, ctr);
  }
}